// Round 18
// baseline (64.131 us; speedup 1.0000x reference)
//
#include <hip/hip_runtime.h>

#define GN 192
#define GNN (GN * GN)
#define GTOT (GN * GN * GN)   // 7,077,888
#define NSLOTS 256
#define NT (GTOT / 2)         // 3,538,944 threads (2 cells each)
#define NBLK (NT / 256)       // 13,824 blocks
#define CHUNK (NBLK / 8)      // 1,728  (13824 % 8 == 0 -> bijective swizzle)

// aux cache-policy bit 1 = NT (non-temporal, evict-first) on gfx94x/95x.
#define AUX_NT 2

typedef int   int32x4_t __attribute__((ext_vector_type(4)));
typedef float floatx4_t __attribute__((ext_vector_type(4)));
typedef float floatx2_t __attribute__((ext_vector_type(2)));
typedef float v2        __attribute__((ext_vector_type(2)));

extern "C" __device__ floatx4_t
llvm_amdgcn_raw_buffer_load_fp32x4(int32x4_t srsrc, int voffset, int soffset,
                                   int aux) __asm("llvm.amdgcn.raw.buffer.load.v4f32");
extern "C" __device__ floatx2_t
llvm_amdgcn_raw_buffer_load_fp32x2(int32x4_t srsrc, int voffset, int soffset,
                                   int aux) __asm("llvm.amdgcn.raw.buffer.load.v2f32");
extern "C" __device__ float
llvm_amdgcn_raw_buffer_load_fp32(int32x4_t srsrc, int voffset, int soffset,
                                 int aux) __asm("llvm.amdgcn.raw.buffer.load.f32");

__device__ __forceinline__ int32x4_t make_srd(const void* ptr, unsigned bytes) {
    int32x4_t r;
    unsigned long long a = (unsigned long long)ptr;
    r.x = (int)(unsigned)(a & 0xFFFFFFFFu);
    r.y = (int)(unsigned)(a >> 32);
    r.z = (int)bytes;          // OOB dwords read 0 (tail overreads safe+unused)
    r.w = 0x00020000;
    return r;
}

__global__ __launch_bounds__(256, 2) void ns_loss_kernel(
    const float* __restrict__ u,      // (N,N,N,3)   stencil-reused -> cached
    const float* __restrict__ uprev,  // (N,N,N,3)   read-once      -> NT
    const float* __restrict__ p,      // (N,N,N)     stencil-reused -> cached
    const float* __restrict__ rho,    // (N,N,N)     read-once      -> NT
    const float* __restrict__ nu,
    const float* __restrict__ h,
    const float* __restrict__ dt,
    const float* __restrict__ grav,
    double* __restrict__ acc)
{
    const int d = blockIdx.x;
    const int o = (d & 7) * CHUNK + (d >> 3);       // XCD-chunked, bijective
    const int g = o * 256 + threadIdx.x;            // pair index < NT
    const int m  = g % 96;                          // 96 pairs per k-line
    const int ln = g / 96;                          // line = i*GN + j
    const int j  = ln % GN;
    const int i  = ln / GN;
    const int k0 = 2 * m;
    const int c0 = ln * GN + k0;
    const int c1 = c0 + 1;
    const int lane = threadIdx.x & 63;

    const int ipb = (i == GN-1) ? c0 - (GN - 1) * GNN : c0 + GNN;
    const int imb = (i == 0)    ? c0 + (GN - 1) * GNN : c0 - GNN;
    const int jpb = (j == GN-1) ? c0 - (GN - 1) * GN  : c0 + GN;
    const int jmb = (j == 0)    ? c0 + (GN - 1) * GN  : c0 - GN;

    const int32x4_t srd_u  = make_srd(u,     (unsigned)GTOT * 12u);
    const int32x4_t srd_up = make_srd(uprev, (unsigned)GTOT * 12u);
    const int32x4_t srd_p  = make_srd(p,     (unsigned)GTOT * 4u);
    const int32x4_t srd_r  = make_srd(rho,   (unsigned)GTOT * 4u);

    // ---- 18 bulk loads (z-halos come from lane shuffles, not memory) ----
    const floatx4_t B  = llvm_amdgcn_raw_buffer_load_fp32x4(srd_u, 12 * c0, 0, 0);
    const floatx4_t C2 = llvm_amdgcn_raw_buffer_load_fp32x4(srd_u, 12 * c0 + 16, 0, 0);
    const floatx4_t E1 = llvm_amdgcn_raw_buffer_load_fp32x4(srd_u, 12 * ipb, 0, 0);
    const floatx4_t E2 = llvm_amdgcn_raw_buffer_load_fp32x4(srd_u, 12 * ipb + 16, 0, 0);
    const floatx4_t G1 = llvm_amdgcn_raw_buffer_load_fp32x4(srd_u, 12 * imb, 0, 0);
    const floatx4_t G2 = llvm_amdgcn_raw_buffer_load_fp32x4(srd_u, 12 * imb + 16, 0, 0);
    const floatx4_t I1 = llvm_amdgcn_raw_buffer_load_fp32x4(srd_u, 12 * jpb, 0, 0);
    const floatx4_t I2 = llvm_amdgcn_raw_buffer_load_fp32x4(srd_u, 12 * jpb + 16, 0, 0);
    const floatx4_t K1 = llvm_amdgcn_raw_buffer_load_fp32x4(srd_u, 12 * jmb, 0, 0);
    const floatx4_t K2 = llvm_amdgcn_raw_buffer_load_fp32x4(srd_u, 12 * jmb + 16, 0, 0);
    const floatx4_t M  = llvm_amdgcn_raw_buffer_load_fp32x4(srd_up, 12 * c0,      0, AUX_NT);
    const floatx4_t M2 = llvm_amdgcn_raw_buffer_load_fp32x4(srd_up, 12 * c0 + 16, 0, AUX_NT);
    const floatx2_t P0  = llvm_amdgcn_raw_buffer_load_fp32x2(srd_p, 4 * c0, 0, 0);
    const floatx2_t Pip = llvm_amdgcn_raw_buffer_load_fp32x2(srd_p, 4 * ipb, 0, 0);
    const floatx2_t Pim = llvm_amdgcn_raw_buffer_load_fp32x2(srd_p, 4 * imb, 0, 0);
    const floatx2_t Pjp = llvm_amdgcn_raw_buffer_load_fp32x2(srd_p, 4 * jpb, 0, 0);
    const floatx2_t Pjm = llvm_amdgcn_raw_buffer_load_fp32x2(srd_p, 4 * jmb, 0, 0);
    const floatx2_t RR  = llvm_amdgcn_raw_buffer_load_fp32x2(srd_r, 4 * c0, 0, AUX_NT);

    // uniform scalars
    const float h0 = h[0], h1v = h[1], h2v = h[2];
    const float i2h0 = 0.5f / h0, i2h1 = 0.5f / h1v, i2h2 = 0.5f / h2v;
    const float ihs0 = 1.0f / (h0 * h0), ihs1 = 1.0f / (h1v * h1v), ihs2 = 1.0f / (h2v * h2v);
    const float invdt = 1.0f / dt[0];
    const float nu0 = nu[0];
    const float g0 = grav[0], g1v = grav[1], g2v = grav[2];
    const float s2h = 2.0f * (ihs0 + ihs1 + ihs2);

    __builtin_amdgcn_sched_barrier(0);

    // cell components
    const float c0x = B.x,  c0y = B.y,  c0z = B.z;
    const float c1x = B.w,  c1y = C2.x, c1z = C2.y;

    // ---- z-halos via intra-wave shuffles ----
    v2 zmx = {__shfl_up(c1x, 1), c0x};
    v2 zmy = {__shfl_up(c1y, 1), c0y};
    v2 zmz = {__shfl_up(c1z, 1), c0z};
    v2 zpx = {c1x, __shfl_down(c0x, 1)};
    v2 zpy = {c1y, __shfl_down(c0y, 1)};
    v2 zpz = {c1z, __shfl_down(c0z, 1)};
    v2 pzm2 = {__shfl_up((float)P0.y, 1), P0.x};
    v2 pzp2 = {P0.y, __shfl_down((float)P0.x, 1)};

    // boundary lanes: k-wrap (m==0 / m==95) and wave edge (lane 0 / 63)
    if (m == 0 || lane == 0) {
        const int zmc = (m == 0) ? c0 + (GN - 1) : c0 - 1;
        const floatx4_t A = llvm_amdgcn_raw_buffer_load_fp32x4(srd_u, 12 * zmc, 0, 0);
        zmx.x = A.x; zmy.x = A.y; zmz.x = A.z;
        pzm2.x = llvm_amdgcn_raw_buffer_load_fp32(srd_p, 4 * zmc, 0, 0);
    }
    if (m == 95 || lane == 63) {
        const int zpc = (m == 95) ? c1 - (GN - 1) : c1 + 1;
        const floatx4_t D = llvm_amdgcn_raw_buffer_load_fp32x4(srd_u, 12 * zpc, 0, 0);
        zpx.y = D.x; zpy.y = D.y; zpz.y = D.z;
        pzp2.y = llvm_amdgcn_raw_buffer_load_fp32(srd_p, 4 * zpc, 0, 0);
    }

    // ---- pack pair into v2 lanes (.x = cell0, .y = cell1) ----
    const v2 ucx = {c0x, c1x}, ucy = {c0y, c1y}, ucz = {c0z, c1z};
    const v2 xpx = {E1.x, E1.w}, xpy = {E1.y, E2.x}, xpz = {E1.z, E2.y};
    const v2 xmx = {G1.x, G1.w}, xmy = {G1.y, G2.x}, xmz = {G1.z, G2.y};
    const v2 ypx = {I1.x, I1.w}, ypy = {I1.y, I2.x}, ypz = {I1.z, I2.y};
    const v2 ymx = {K1.x, K1.w}, ymy = {K1.y, K2.x}, ymz = {K1.z, K2.y};
    const v2 upx = {M.x, M.w},  upy = {M.y, M2.x}, upz = {M.z, M2.y};

    // ---- packed stencil math (validated form) ----
    v2 dXx = (xpx - xmx) * i2h0, dXy = (xpy - xmy) * i2h0, dXz = (xpz - xmz) * i2h0;
    v2 dYx = (ypx - ymx) * i2h1, dYy = (ypy - ymy) * i2h1, dYz = (ypz - ymz) * i2h1;
    v2 dZx = (zpx - zmx) * i2h2, dZy = (zpy - zmy) * i2h2, dZz = (zpz - zmz) * i2h2;

    v2 lapx = (xpx + xmx) * ihs0 + (ypx + ymx) * ihs1 + (zpx + zmx) * ihs2 - ucx * s2h;
    v2 lapy = (xpy + xmy) * ihs0 + (ypy + ymy) * ihs1 + (zpy + zmy) * ihs2 - ucy * s2h;
    v2 lapz = (xpz + xmz) * ihs0 + (ypz + ymz) * ihs1 + (zpz + zmz) * ihs2 - ucz * s2h;

    v2 convx = ucx * dXx + ucy * dYx + ucz * dZx;
    v2 convy = ucx * dXy + ucy * dYy + ucz * dZy;
    v2 convz = ucx * dXz + ucy * dYz + ucz * dZz;

    v2 dpx = (Pip - Pim) * i2h0;
    v2 dpy = (Pjp - Pjm) * i2h1;
    v2 dpz = (pzp2 - pzm2) * i2h2;

    v2 irho;
    irho.x = __builtin_amdgcn_rcpf(RR.x + 1e-8f);
    irho.y = __builtin_amdgcn_rcpf(RR.y + 1e-8f);

    v2 Rx = (ucx - upx) * invdt + convx + dpx * irho - lapx * nu0 - g0;
    v2 Ry = (ucy - upy) * invdt + convy + dpy * irho - lapy * nu0 - g1v;
    v2 Rz = (ucz - upz) * invdt + convz + dpz * irho - lapz * nu0 - g2v;
    v2 Rc = dXx + dYy + dZz;

    v2 m2 = Rx * Rx + Ry * Ry + Rz * Rz;
    v2 c2 = Rc * Rc;
    float msum = m2.x + m2.y;
    float csum = c2.x + c2.y;

    // wave(64) reduce in fp32, then block, then one atomic pair
    #pragma unroll
    for (int off = 32; off > 0; off >>= 1) {
        msum += __shfl_down(msum, off);
        csum += __shfl_down(csum, off);
    }

    __shared__ double smom[4], scont[4];
    const int wid = threadIdx.x >> 6;
    if (lane == 0) { smom[wid] = (double)msum; scont[wid] = (double)csum; }
    __syncthreads();
    if (threadIdx.x == 0) {
        const double mm = smom[0] + smom[1] + smom[2] + smom[3];
        const double cc = scont[0] + scont[1] + scont[2] + scont[3];
        double* slot = acc + 2 * (blockIdx.x & (NSLOTS - 1));
        unsafeAtomicAdd(slot, mm);
        unsafeAtomicAdd(slot + 1, cc);
    }
}

__global__ __launch_bounds__(256) void ns_finalize_kernel(const double* __restrict__ acc,
                                                          float* __restrict__ out)
{
    const int tid = threadIdx.x;
    double mom = acc[2 * tid];
    double cont = acc[2 * tid + 1];
    #pragma unroll
    for (int off = 32; off > 0; off >>= 1) {
        mom  += __shfl_down(mom, off);
        cont += __shfl_down(cont, off);
    }
    __shared__ double smom[4], scont[4];
    const int wid = tid >> 6;
    const int lane = tid & 63;
    if (lane == 0) { smom[wid] = mom; scont[wid] = cont; }
    __syncthreads();
    if (tid == 0) {
        const double m = (smom[0] + smom[1] + smom[2] + smom[3]) / (double)GTOT;
        const double c = (scont[0] + scont[1] + scont[2] + scont[3]) / (double)GTOT;
        out[0] = (float)(m + 10.0 * c);
        out[1] = (float)m;
        out[2] = (float)c;
    }
}

extern "C" void kernel_launch(void* const* d_in, const int* in_sizes, int n_in,
                              void* d_out, int out_size, void* d_ws, size_t ws_size,
                              hipStream_t stream)
{
    const float* u     = (const float*)d_in[0];
    const float* uprev = (const float*)d_in[1];
    const float* p     = (const float*)d_in[2];
    const float* rho   = (const float*)d_in[3];
    const float* nu    = (const float*)d_in[4];
    const float* h     = (const float*)d_in[5];
    const float* dt    = (const float*)d_in[6];
    const float* grav  = (const float*)d_in[7];

    double* acc = (double*)d_ws;

    (void)hipMemsetAsync(d_ws, 0, NSLOTS * 2 * sizeof(double), stream);

    ns_loss_kernel<<<NBLK, 256, 0, stream>>>(u, uprev, p, rho, nu, h, dt, grav, acc);
    ns_finalize_kernel<<<1, 256, 0, stream>>>(acc, (float*)d_out);
}

// Round 19
// 49.663 us; speedup vs baseline: 1.2913x; 1.2913x over previous
//
#include <hip/hip_runtime.h>

#define GN 192
#define GNN (GN * GN)
#define GTOT (GN * GN * GN)   // 7,077,888
#define NSLOTS 256
#define NT (GTOT / 2)         // 3,538,944 threads (2 cells each)
#define NBLK (NT / 256)       // 13,824 blocks
#define CHUNK (NBLK / 8)      // 1,728  (13824 % 8 == 0 -> bijective swizzle)

typedef int   int32x4_t __attribute__((ext_vector_type(4)));
typedef float floatx4_t __attribute__((ext_vector_type(4)));
typedef float floatx2_t __attribute__((ext_vector_type(2)));
typedef float v2        __attribute__((ext_vector_type(2)));

extern "C" __device__ floatx4_t
llvm_amdgcn_raw_buffer_load_fp32x4(int32x4_t srsrc, int voffset, int soffset,
                                   int aux) __asm("llvm.amdgcn.raw.buffer.load.v4f32");
extern "C" __device__ floatx2_t
llvm_amdgcn_raw_buffer_load_fp32x2(int32x4_t srsrc, int voffset, int soffset,
                                   int aux) __asm("llvm.amdgcn.raw.buffer.load.v2f32");
extern "C" __device__ float
llvm_amdgcn_raw_buffer_load_fp32(int32x4_t srsrc, int voffset, int soffset,
                                 int aux) __asm("llvm.amdgcn.raw.buffer.load.f32");

__device__ __forceinline__ int32x4_t make_srd(const void* ptr, unsigned bytes) {
    int32x4_t r;
    unsigned long long a = (unsigned long long)ptr;
    r.x = (int)(unsigned)(a & 0xFFFFFFFFu);
    r.y = (int)(unsigned)(a >> 32);
    r.z = (int)bytes;          // OOB dwords read 0 (tail overreads safe+unused)
    r.w = 0x00020000;
    return r;
}

__global__ __launch_bounds__(256, 2) void ns_loss_kernel(
    const float* __restrict__ u,      // (N,N,N,3)
    const float* __restrict__ uprev,  // (N,N,N,3)
    const float* __restrict__ p,      // (N,N,N)
    const float* __restrict__ rho,    // (N,N,N)
    const float* __restrict__ nu,
    const float* __restrict__ h,
    const float* __restrict__ dt,
    const float* __restrict__ grav,
    double* __restrict__ acc)
{
    const int d = blockIdx.x;
    const int o = (d & 7) * CHUNK + (d >> 3);       // XCD-chunked, bijective
    const int g = o * 256 + threadIdx.x;            // pair index < NT
    const int m  = g % 96;                          // 96 pairs per k-line
    const int ln = g / 96;                          // line = i*GN + j
    const int j  = ln % GN;
    const int i  = ln / GN;
    const int k0 = 2 * m;
    const int c0 = ln * GN + k0;
    const int c1 = c0 + 1;
    const int lane = threadIdx.x & 63;

    const int ipb = (i == GN-1) ? c0 - (GN - 1) * GNN : c0 + GNN;
    const int imb = (i == 0)    ? c0 + (GN - 1) * GNN : c0 - GNN;
    const int jpb = (j == GN-1) ? c0 - (GN - 1) * GN  : c0 + GN;
    const int jmb = (j == 0)    ? c0 + (GN - 1) * GN  : c0 - GN;

    const int32x4_t srd_u  = make_srd(u,     (unsigned)GTOT * 12u);
    const int32x4_t srd_up = make_srd(uprev, (unsigned)GTOT * 12u);
    const int32x4_t srd_p  = make_srd(p,     (unsigned)GTOT * 4u);
    const int32x4_t srd_r  = make_srd(rho,   (unsigned)GTOT * 4u);

    // ---- 18 bulk loads (z-halos come from lane shuffles, not memory) ----
    const floatx4_t B  = llvm_amdgcn_raw_buffer_load_fp32x4(srd_u, 12 * c0, 0, 0);
    const floatx4_t C2 = llvm_amdgcn_raw_buffer_load_fp32x4(srd_u, 12 * c0 + 16, 0, 0);
    const floatx4_t E1 = llvm_amdgcn_raw_buffer_load_fp32x4(srd_u, 12 * ipb, 0, 0);
    const floatx4_t E2 = llvm_amdgcn_raw_buffer_load_fp32x4(srd_u, 12 * ipb + 16, 0, 0);
    const floatx4_t G1 = llvm_amdgcn_raw_buffer_load_fp32x4(srd_u, 12 * imb, 0, 0);
    const floatx4_t G2 = llvm_amdgcn_raw_buffer_load_fp32x4(srd_u, 12 * imb + 16, 0, 0);
    const floatx4_t I1 = llvm_amdgcn_raw_buffer_load_fp32x4(srd_u, 12 * jpb, 0, 0);
    const floatx4_t I2 = llvm_amdgcn_raw_buffer_load_fp32x4(srd_u, 12 * jpb + 16, 0, 0);
    const floatx4_t K1 = llvm_amdgcn_raw_buffer_load_fp32x4(srd_u, 12 * jmb, 0, 0);
    const floatx4_t K2 = llvm_amdgcn_raw_buffer_load_fp32x4(srd_u, 12 * jmb + 16, 0, 0);
    const floatx4_t M  = llvm_amdgcn_raw_buffer_load_fp32x4(srd_up, 12 * c0, 0, 0);
    const floatx4_t M2 = llvm_amdgcn_raw_buffer_load_fp32x4(srd_up, 12 * c0 + 16, 0, 0);
    const floatx2_t P0  = llvm_amdgcn_raw_buffer_load_fp32x2(srd_p, 4 * c0, 0, 0);
    const floatx2_t Pip = llvm_amdgcn_raw_buffer_load_fp32x2(srd_p, 4 * ipb, 0, 0);
    const floatx2_t Pim = llvm_amdgcn_raw_buffer_load_fp32x2(srd_p, 4 * imb, 0, 0);
    const floatx2_t Pjp = llvm_amdgcn_raw_buffer_load_fp32x2(srd_p, 4 * jpb, 0, 0);
    const floatx2_t Pjm = llvm_amdgcn_raw_buffer_load_fp32x2(srd_p, 4 * jmb, 0, 0);
    const floatx2_t RR  = llvm_amdgcn_raw_buffer_load_fp32x2(srd_r, 4 * c0, 0, 0);

    // uniform scalars
    const float h0 = h[0], h1v = h[1], h2v = h[2];
    const float i2h0 = 0.5f / h0, i2h1 = 0.5f / h1v, i2h2 = 0.5f / h2v;
    const float ihs0 = 1.0f / (h0 * h0), ihs1 = 1.0f / (h1v * h1v), ihs2 = 1.0f / (h2v * h2v);
    const float invdt = 1.0f / dt[0];
    const float nu0 = nu[0];
    const float g0 = grav[0], g1v = grav[1], g2v = grav[2];
    const float s2h = 2.0f * (ihs0 + ihs1 + ihs2);

    __builtin_amdgcn_sched_barrier(0);

    // cell components
    const float c0x = B.x,  c0y = B.y,  c0z = B.z;
    const float c1x = B.w,  c1y = C2.x, c1z = C2.y;

    // ---- z-halos via intra-wave shuffles ----
    v2 zmx = {__shfl_up(c1x, 1), c0x};
    v2 zmy = {__shfl_up(c1y, 1), c0y};
    v2 zmz = {__shfl_up(c1z, 1), c0z};
    v2 zpx = {c1x, __shfl_down(c0x, 1)};
    v2 zpy = {c1y, __shfl_down(c0y, 1)};
    v2 zpz = {c1z, __shfl_down(c0z, 1)};
    v2 pzm2 = {__shfl_up((float)P0.y, 1), P0.x};
    v2 pzp2 = {P0.y, __shfl_down((float)P0.x, 1)};

    // boundary lanes: k-wrap (m==0 / m==95) and wave edge (lane 0 / 63)
    if (m == 0 || lane == 0) {
        const int zmc = (m == 0) ? c0 + (GN - 1) : c0 - 1;
        const floatx4_t A = llvm_amdgcn_raw_buffer_load_fp32x4(srd_u, 12 * zmc, 0, 0);
        zmx.x = A.x; zmy.x = A.y; zmz.x = A.z;
        pzm2.x = llvm_amdgcn_raw_buffer_load_fp32(srd_p, 4 * zmc, 0, 0);
    }
    if (m == 95 || lane == 63) {
        const int zpc = (m == 95) ? c1 - (GN - 1) : c1 + 1;
        const floatx4_t D = llvm_amdgcn_raw_buffer_load_fp32x4(srd_u, 12 * zpc, 0, 0);
        zpx.y = D.x; zpy.y = D.y; zpz.y = D.z;
        pzp2.y = llvm_amdgcn_raw_buffer_load_fp32(srd_p, 4 * zpc, 0, 0);
    }

    // ---- pack pair into v2 lanes (.x = cell0, .y = cell1) ----
    const v2 ucx = {c0x, c1x}, ucy = {c0y, c1y}, ucz = {c0z, c1z};
    const v2 xpx = {E1.x, E1.w}, xpy = {E1.y, E2.x}, xpz = {E1.z, E2.y};
    const v2 xmx = {G1.x, G1.w}, xmy = {G1.y, G2.x}, xmz = {G1.z, G2.y};
    const v2 ypx = {I1.x, I1.w}, ypy = {I1.y, I2.x}, ypz = {I1.z, I2.y};
    const v2 ymx = {K1.x, K1.w}, ymy = {K1.y, K2.x}, ymz = {K1.z, K2.y};
    const v2 upx = {M.x, M.w},  upy = {M.y, M2.x}, upz = {M.z, M2.y};

    // ---- packed stencil math (validated form) ----
    v2 dXx = (xpx - xmx) * i2h0, dXy = (xpy - xmy) * i2h0, dXz = (xpz - xmz) * i2h0;
    v2 dYx = (ypx - ymx) * i2h1, dYy = (ypy - ymy) * i2h1, dYz = (ypz - ymz) * i2h1;
    v2 dZx = (zpx - zmx) * i2h2, dZy = (zpy - zmy) * i2h2, dZz = (zpz - zmz) * i2h2;

    v2 lapx = (xpx + xmx) * ihs0 + (ypx + ymx) * ihs1 + (zpx + zmx) * ihs2 - ucx * s2h;
    v2 lapy = (xpy + xmy) * ihs0 + (ypy + ymy) * ihs1 + (zpy + zmy) * ihs2 - ucy * s2h;
    v2 lapz = (xpz + xmz) * ihs0 + (ypz + ymz) * ihs1 + (zpz + zmz) * ihs2 - ucz * s2h;

    v2 convx = ucx * dXx + ucy * dYx + ucz * dZx;
    v2 convy = ucx * dXy + ucy * dYy + ucz * dZy;
    v2 convz = ucx * dXz + ucy * dYz + ucz * dZz;

    v2 dpx = (Pip - Pim) * i2h0;
    v2 dpy = (Pjp - Pjm) * i2h1;
    v2 dpz = (pzp2 - pzm2) * i2h2;

    v2 irho;
    irho.x = __builtin_amdgcn_rcpf(RR.x + 1e-8f);
    irho.y = __builtin_amdgcn_rcpf(RR.y + 1e-8f);

    v2 Rx = (ucx - upx) * invdt + convx + dpx * irho - lapx * nu0 - g0;
    v2 Ry = (ucy - upy) * invdt + convy + dpy * irho - lapy * nu0 - g1v;
    v2 Rz = (ucz - upz) * invdt + convz + dpz * irho - lapz * nu0 - g2v;
    v2 Rc = dXx + dYy + dZz;

    v2 m2 = Rx * Rx + Ry * Ry + Rz * Rz;
    v2 c2 = Rc * Rc;
    float msum = m2.x + m2.y;
    float csum = c2.x + c2.y;

    // wave(64) reduce in fp32, then block, then one atomic pair
    #pragma unroll
    for (int off = 32; off > 0; off >>= 1) {
        msum += __shfl_down(msum, off);
        csum += __shfl_down(csum, off);
    }

    __shared__ double smom[4], scont[4];
    const int wid = threadIdx.x >> 6;
    if (lane == 0) { smom[wid] = (double)msum; scont[wid] = (double)csum; }
    __syncthreads();
    if (threadIdx.x == 0) {
        const double mm = smom[0] + smom[1] + smom[2] + smom[3];
        const double cc = scont[0] + scont[1] + scont[2] + scont[3];
        double* slot = acc + 2 * (blockIdx.x & (NSLOTS - 1));
        unsafeAtomicAdd(slot, mm);
        unsafeAtomicAdd(slot + 1, cc);
    }
}

__global__ __launch_bounds__(256) void ns_finalize_kernel(const double* __restrict__ acc,
                                                          float* __restrict__ out)
{
    const int tid = threadIdx.x;
    double mom = acc[2 * tid];
    double cont = acc[2 * tid + 1];
    #pragma unroll
    for (int off = 32; off > 0; off >>= 1) {
        mom  += __shfl_down(mom, off);
        cont += __shfl_down(cont, off);
    }
    __shared__ double smom[4], scont[4];
    const int wid = tid >> 6;
    const int lane = tid & 63;
    if (lane == 0) { smom[wid] = mom; scont[wid] = cont; }
    __syncthreads();
    if (tid == 0) {
        const double m = (smom[0] + smom[1] + smom[2] + smom[3]) / (double)GTOT;
        const double c = (scont[0] + scont[1] + scont[2] + scont[3]) / (double)GTOT;
        out[0] = (float)(m + 10.0 * c);
        out[1] = (float)m;
        out[2] = (float)c;
    }
}

extern "C" void kernel_launch(void* const* d_in, const int* in_sizes, int n_in,
                              void* d_out, int out_size, void* d_ws, size_t ws_size,
                              hipStream_t stream)
{
    const float* u     = (const float*)d_in[0];
    const float* uprev = (const float*)d_in[1];
    const float* p     = (const float*)d_in[2];
    const float* rho   = (const float*)d_in[3];
    const float* nu    = (const float*)d_in[4];
    const float* h     = (const float*)d_in[5];
    const float* dt    = (const float*)d_in[6];
    const float* grav  = (const float*)d_in[7];

    double* acc = (double*)d_ws;

    (void)hipMemsetAsync(d_ws, 0, NSLOTS * 2 * sizeof(double), stream);

    ns_loss_kernel<<<NBLK, 256, 0, stream>>>(u, uprev, p, rho, nu, h, dt, grav, acc);
    ns_finalize_kernel<<<1, 256, 0, stream>>>(acc, (float*)d_out);
}